// Round 8
// baseline (229.878 us; speedup 1.0000x reference)
//
#include <hip/hip_runtime.h>
#include <hip/hip_bf16.h>
#include <stdint.h>

// Problem constants
#define BS   4
#define LSEQ 2048
#define HID  1024
#define NH   16
#define HD   64
#define M_TOT (BS * LSEQ)   // 8192
#define NKV   (NH * HD)     // 1024
#define NIT   24            // 48 K-tiles of 64 (K_eff = 3*1024), 2 per iteration

typedef __attribute__((ext_vector_type(8))) short short8x;   // 8 bf16
typedef __attribute__((ext_vector_type(4))) float f32x4;     // MFMA accum

__device__ __forceinline__ float relu_f(float x) { return x > 0.0f ? x : 0.0f; }

__device__ __forceinline__ ushort bf16_rne(float f) {
    uint32_t x = __float_as_uint(f);
    return (ushort)((x + 0x7FFFu + ((x >> 16) & 1u)) >> 16);
}
__device__ __forceinline__ float bf16_to_f(ushort h) {
    return __uint_as_float((uint32_t)h << 16);
}

__device__ __forceinline__ void gload_lds16(const void* g, void* l) {
    typedef __attribute__((address_space(1))) const uint32_t GU;
    typedef __attribute__((address_space(3))) uint32_t LU;
    __builtin_amdgcn_global_load_lds((GU*)g, (LU*)l, 16, 0, 0);
}

// ---------------- fused prep: A hi/lo split + both W hi/lo transposed splits ----------------
__global__ __launch_bounds__(256) void prep(
    const float* __restrict__ A,
    const float* __restrict__ Wv, const float* __restrict__ Wk,
    ushort* __restrict__ Ahi, ushort* __restrict__ Alo,
    ushort* __restrict__ WvhiT, ushort* __restrict__ WvloT,
    ushort* __restrict__ WkhiT, ushort* __restrict__ WkloT)
{
    __shared__ float t[64][65];
    const int bid = blockIdx.x;
    const int tid = threadIdx.x;
    if (bid < 8192) {
        // A split: one float4 per thread
        int i = bid * 256 + tid;
        float4 v = ((const float4*)A)[i];
        ushort4 h, l;
        h.x = bf16_rne(v.x); l.x = bf16_rne(v.x - bf16_to_f(h.x));
        h.y = bf16_rne(v.y); l.y = bf16_rne(v.y - bf16_to_f(h.y));
        h.z = bf16_rne(v.z); l.z = bf16_rne(v.z - bf16_to_f(h.z));
        h.w = bf16_rne(v.w); l.w = bf16_rne(v.w - bf16_to_f(h.w));
        ((ushort4*)Ahi)[i] = h;
        ((ushort4*)Alo)[i] = l;
    } else {
        // W transpose + split: 512 blocks, 64x64 tiles
        int idx = bid - 8192;                 // 0..511
        const float* W  = (idx < 256) ? Wv : Wk;
        ushort* hiT     = (idx < 256) ? WvhiT : WkhiT;
        ushort* loT     = (idx < 256) ? WvloT : WkloT;
        int tt = idx & 255;
        int k0 = (tt >> 4) * 64, n0 = (tt & 15) * 64;
#pragma unroll
        for (int it = 0; it < 4; ++it) {
            int r = it * 16 + (tid >> 4);
            int c = (tid & 15) * 4;
            float4 v = *(const float4*)&W[(size_t)(k0 + r) * NKV + n0 + c];
            t[r][c] = v.x; t[r][c + 1] = v.y; t[r][c + 2] = v.z; t[r][c + 3] = v.w;
        }
        __syncthreads();
        int n  = tid >> 2;            // 0..63
        int kc = (tid & 3) * 16;      // 0,16,32,48
        ushort hb[16], lb[16];
#pragma unroll
        for (int j = 0; j < 16; ++j) {
            float f = t[kc + j][n];
            ushort h = bf16_rne(f);
            hb[j] = h;
            lb[j] = bf16_rne(f - bf16_to_f(h));
        }
        size_t o = (size_t)(n0 + n) * 1024 + k0 + kc;
        *(uint4*)&hiT[o]     = *(uint4*)&hb[0];
        *(uint4*)&hiT[o + 8] = *(uint4*)&hb[8];
        *(uint4*)&loT[o]     = *(uint4*)&lb[0];
        *(uint4*)&loT[o + 8] = *(uint4*)&lb[8];
    }
}

// ---------------- 256x256 8-phase split-bf16 MFMA GEMM ----------------
// grid (32, 8): y 0..3 -> V path (Wv), y 4..7 -> K path (Wk, dot+threshold)
// C = Ahi@Whi + Alo@Whi + Ahi@Wlo over 48 K-tiles of 64.
// 8 waves (2M x 4N), per-wave output 128x64. Even K-tiles buf0, odd buf1.
//
// m196-style fine interleave: ds_reads front-loaded (P1: A.h0+B01 = 12,
// P2: A.h1->a2_f + B23 = 12; P3/P4 pure MFMA), so every LDS region's last
// read completes by P2 (buf0) / P6 (buf1). Stage exactly ONE half-tile
// (2 loads/thread) per phase:
//   P1: B(kt1).h0 [i>0]   P2: B(kt1).h1 [i>0]
//   P3: A(kt0+2).h0       P4: A(kt0+2).h1   + vmcnt(4)
//   P5: B(kt0+2).h0       P6: B(kt0+2).h1
//   P7: A(kt1+2).h0       P8: A(kt1+2).h1   + vmcnt(4)
// vmcnt(4) at P4: 12 outstanding {A(kt1),B(kt1),A(kt0+2)}; drain 8 oldest
// = kt1 complete before P5 reads. Symmetric at P8 for next kt0.
__global__ __launch_bounds__(512, 2) void mfma_gemm(
    const ushort* __restrict__ Ahi, const ushort* __restrict__ Alo,
    const ushort* __restrict__ WvhiT, const ushort* __restrict__ WvloT,
    const ushort* __restrict__ WkhiT, const ushort* __restrict__ WkloT,
    const float* __restrict__ bv, const float* __restrict__ bk,
    const float* __restrict__ RH,
    float* __restrict__ V1, unsigned char* __restrict__ validB)
{
    __shared__ ushort LA[2][256 * 64];   // 2 x 32 KiB
    __shared__ ushort LB[2][256 * 64];   // 2 x 32 KiB

    const int tid  = threadIdx.x;        // 0..511
    const int lane = tid & 63;
    const int wv   = tid >> 6;           // 0..7
    const int wm   = wv >> 2;            // 0/1
    const int wn   = wv & 3;             // 0..3
    const int bm   = blockIdx.x;
    const bool kpath = (blockIdx.y >= 4);
    const int bnl  = kpath ? (blockIdx.y - 4) : blockIdx.y;

    const ushort* Whi  = kpath ? WkhiT : WvhiT;
    const ushort* Wlo  = kpath ? WkloT : WvloT;
    const float*  bias = kpath ? bk : bv;

    f32x4 acc[8][4];
    const f32x4 zz = {0.f, 0.f, 0.f, 0.f};
#pragma unroll
    for (int i = 0; i < 8; ++i)
#pragma unroll
        for (int j = 0; j < 4; ++j) acc[i][j] = zz;

    // Lane-constant swizzled read-chunk offsets (shorts).
    const int rc0 = ((0 + (lane >> 4)) ^ (lane & 7)) * 8;   // k2=0
    const int rc1 = ((4 + (lane >> 4)) ^ (lane & 7)) * 8;   // k2=1

    auto Asrc = [&](int kt, int half) -> const ushort* {
        const ushort* base = ((kt >> 4) == 1) ? Alo : Ahi;
        return base + (size_t)(bm * 256 + half * 128) * 1024 + ((kt & 15) << 6);
    };
    auto Bsrc = [&](int kt, int half) -> const ushort* {
        const ushort* base = ((kt >> 4) == 2) ? Wlo : Whi;
        return base + (size_t)(bnl * 256 + half * 128) * 1024 + ((kt & 15) << 6);
    };

#define STAGE_HALF(dst, src) do {                                              \
    _Pragma("unroll")                                                          \
    for (int it_ = 0; it_ < 2; ++it_) {                                        \
        int f_ = it_ * 512 + tid;                                              \
        int r_ = f_ >> 3, c_ = f_ & 7;                                         \
        gload_lds16((src) + (size_t)r_ * 1024 + ((c_ ^ (r_ & 7)) << 3),        \
                    (dst) + (size_t)(it_ * 512 + wv * 64) * 8);                \
    }                                                                          \
} while (0)

#define READ_A(buf, dst, half) do {                                            \
    _Pragma("unroll")                                                          \
    for (int mi_ = 0; mi_ < 4; ++mi_) {                                        \
        int row_ = wm * 128 + (half) * 64 + mi_ * 16 + (lane & 15);            \
        const ushort* b_ = &LA[buf][row_ * 64];                                \
        dst[mi_][0] = *(const short8x*)(b_ + rc0);                             \
        dst[mi_][1] = *(const short8x*)(b_ + rc1);                             \
    }                                                                          \
} while (0)

#define READ_B2(buf, ni0) do {                                                 \
    _Pragma("unroll")                                                          \
    for (int nj_ = 0; nj_ < 2; ++nj_) {                                        \
        int ni_ = (ni0) + nj_;                                                 \
        int row_ = wn * 64 + ni_ * 16 + (lane & 15);                           \
        const ushort* b_ = &LB[buf][row_ * 64];                                \
        b_f[ni_][0] = *(const short8x*)(b_ + rc0);                             \
        b_f[ni_][1] = *(const short8x*)(b_ + rc1);                             \
    }                                                                          \
} while (0)

#define MFMA_QUAD(areg, mh, nh) do {                                           \
    _Pragma("unroll")                                                          \
    for (int k2_ = 0; k2_ < 2; ++k2_)                                          \
        _Pragma("unroll")                                                      \
        for (int mi_ = 0; mi_ < 4; ++mi_)                                      \
            _Pragma("unroll")                                                  \
            for (int nj_ = 0; nj_ < 2; ++nj_) {                                \
                int ni_ = (nh) * 2 + nj_;                                      \
                acc[(mh) * 4 + mi_][ni_] =                                     \
                    __builtin_amdgcn_mfma_f32_16x16x32_bf16(                   \
                        areg[mi_][k2_], b_f[ni_][k2_], acc[(mh) * 4 + mi_][ni_],\
                        0, 0, 0);                                              \
            }                                                                  \
} while (0)

#define PHASE_SYNC()                                                           \
    __builtin_amdgcn_s_barrier();                                              \
    asm volatile("s_waitcnt lgkmcnt(0)" ::: "memory");                         \
    __builtin_amdgcn_sched_barrier(0);                                         \
    __builtin_amdgcn_s_setprio(1)

#define PHASE_END()                                                            \
    __builtin_amdgcn_s_setprio(0);                                             \
    __builtin_amdgcn_s_barrier()

    short8x a_f[4][2], a2_f[4][2], b_f[4][2];

    // Prologue: stage kt0 (first 8 loads) then kt1 (next 8).
    STAGE_HALF(&LA[0][0],    Asrc(0, 0));
    STAGE_HALF(&LA[0][8192], Asrc(0, 1));
    STAGE_HALF(&LB[0][0],    Bsrc(0, 0));
    STAGE_HALF(&LB[0][8192], Bsrc(0, 1));
    STAGE_HALF(&LA[1][0],    Asrc(1, 0));
    STAGE_HALF(&LA[1][8192], Asrc(1, 1));
    STAGE_HALF(&LB[1][0],    Bsrc(1, 0));
    STAGE_HALF(&LB[1][8192], Bsrc(1, 1));
    asm volatile("s_waitcnt vmcnt(8)" ::: "memory");   // kt0 landed
    __builtin_amdgcn_s_barrier();

#pragma unroll 1
    for (int i = 0; i < NIT; ++i) {
        const int kt0 = 2 * i;
        const int kt1 = 2 * i + 1;
        const bool st = (i < NIT - 1);

        // ---- P1: reads A.h0 + B01 of kt0; stage B(kt1).h0 ----
        READ_A(0, a_f, 0); READ_B2(0, 0);
        if (i > 0) STAGE_HALF(&LB[1][0], Bsrc(kt1, 0));
        PHASE_SYNC();
        MFMA_QUAD(a_f, 0, 0);
        PHASE_END();

        // ---- P2: reads A.h1 -> a2_f + B23; stage B(kt1).h1 ----
        READ_A(0, a2_f, 1); READ_B2(0, 2);
        if (i > 0) STAGE_HALF(&LB[1][8192], Bsrc(kt1, 1));
        PHASE_SYNC();
        MFMA_QUAD(a_f, 0, 1);
        PHASE_END();

        // ---- P3: pure MFMA; stage A(kt0+2).h0 (LA[0] fully read by P2) ----
        if (st) STAGE_HALF(&LA[0][0], Asrc(kt0 + 2, 0));
        PHASE_SYNC();
        MFMA_QUAD(a2_f, 1, 1);
        PHASE_END();

        // ---- P4: pure MFMA; stage A(kt0+2).h1; vmcnt(4) = kt1 landed ----
        if (st) STAGE_HALF(&LA[0][8192], Asrc(kt0 + 2, 1));
        PHASE_SYNC();
        MFMA_QUAD(a2_f, 1, 0);
        __builtin_amdgcn_s_setprio(0);
        if (st) asm volatile("s_waitcnt vmcnt(4)" ::: "memory");
        else    asm volatile("s_waitcnt vmcnt(0)" ::: "memory");
        __builtin_amdgcn_s_barrier();

        // ---- P5: reads kt1 A.h0 + B01; stage B(kt0+2).h0 (LB[0] free) ----
        READ_A(1, a_f, 0); READ_B2(1, 0);
        if (st) STAGE_HALF(&LB[0][0], Bsrc(kt0 + 2, 0));
        PHASE_SYNC();
        MFMA_QUAD(a_f, 0, 0);
        PHASE_END();

        // ---- P6: reads kt1 A.h1 + B23; stage B(kt0+2).h1 ----
        READ_A(1, a2_f, 1); READ_B2(1, 2);
        if (st) STAGE_HALF(&LB[0][8192], Bsrc(kt0 + 2, 1));
        PHASE_SYNC();
        MFMA_QUAD(a_f, 0, 1);
        PHASE_END();

        // ---- P7: pure MFMA; stage A(kt1+2).h0 (LA[1] fully read by P6) ----
        if (st) STAGE_HALF(&LA[1][0], Asrc(kt1 + 2, 0));
        PHASE_SYNC();
        MFMA_QUAD(a2_f, 1, 1);
        PHASE_END();

        // ---- P8: pure MFMA; stage A(kt1+2).h1; vmcnt(4) = next kt0 landed ----
        if (st) STAGE_HALF(&LA[1][8192], Asrc(kt1 + 2, 1));
        PHASE_SYNC();
        MFMA_QUAD(a2_f, 1, 0);
        __builtin_amdgcn_s_setprio(0);
        if (st) asm volatile("s_waitcnt vmcnt(4)" ::: "memory");
        __builtin_amdgcn_s_barrier();
    }

    // ---- epilogue ----  C/D layout: col = lane&15, row = (lane>>4)*4 + reg
    if (!kpath) {
#pragma unroll
        for (int mi = 0; mi < 8; ++mi)
#pragma unroll
            for (int ni = 0; ni < 4; ++ni) {
                int row0 = bm * 256 + wm * 128 + mi * 16 + (lane >> 4) * 4;
                int col  = bnl * 256 + wn * 64 + ni * 16 + (lane & 15);
                float bc = bias[col];
#pragma unroll
                for (int r = 0; r < 4; ++r)
                    V1[(size_t)(row0 + r) * NKV + col] = relu_f(acc[mi][ni][r] + bc);
            }
    } else {
        const int head = bnl * 4 + wn;     // wave column == one head (64 cols)
        float rhw[4], bcs[4];
#pragma unroll
        for (int ni = 0; ni < 4; ++ni) {
            int ch = ni * 16 + (lane & 15);
            rhw[ni] = RH[head * HD + ch];
            bcs[ni] = bias[head * HD + ch];
        }
#pragma unroll
        for (int mi = 0; mi < 8; ++mi) {
            float s[4];
#pragma unroll
            for (int r = 0; r < 4; ++r) {
                float v = 0.f;
#pragma unroll
                for (int ni = 0; ni < 4; ++ni)
                    v += relu_f(acc[mi][ni][r] + bcs[ni]) * rhw[ni];
                s[r] = v;
            }
#pragma unroll
            for (int m = 1; m < 16; m <<= 1)
#pragma unroll
                for (int r = 0; r < 4; ++r)
                    s[r] += __shfl_xor(s[r], m);
            if ((lane & 15) == 0) {
#pragma unroll
                for (int r = 0; r < 4; ++r) {
                    int grow = bm * 256 + wm * 128 + mi * 16 + (lane >> 4) * 4 + r;
                    int bb = grow >> 11, ll = grow & 2047;
                    validB[((size_t)bb * NH + head) * LSEQ + ll] = (s[r] > 0.5f) ? 1 : 0;
                }
            }
        }
    }
#undef STAGE_HALF
#undef READ_A
#undef READ_B2
#undef MFMA_QUAD
#undef PHASE_SYNC
#undef PHASE_END
}

// ---------------- parallel register-map extraction ----------------
__global__ __launch_bounds__(256) void scan_kernel(
    const unsigned char* __restrict__ validB,
    short* __restrict__ idxb)   // [M_TOT][NH][8]: slots 0..3 fwd, 4..7 bwd
{
    const int bh = blockIdx.x;      // 0..63
    const int b  = bh >> 4;
    const int h  = bh & 15;
    const unsigned char* v = validB + ((size_t)b * NH + h) * LSEQ;

    __shared__ uint64_t words[LSEQ / 64];

    const int tid  = threadIdx.x;
    const int lane = tid & 63;
    const int wv   = tid >> 6;

#pragma unroll
    for (int it = 0; it < LSEQ / 256; ++it) {
        int p = it * 256 + wv * 64 + lane;
        uint64_t m = __ballot(v[p] != 0);
        if (lane == 0) {
            if ((p >> 6) == 0) m &= ~1ull;
            words[p >> 6] = m;
        }
    }
    __syncthreads();

#pragma unroll
    for (int it = 0; it < LSEQ / 256; ++it) {
        int l = it * 256 + tid;
        ushort f[4] = {0, 0, 0, 0};
        ushort g[4] = {0, 0, 0, 0};
        if (l > 0) {
            {   // forward: last 4 set bits <= l
                int wi = l >> 6, bi = l & 63;
                uint64_t m = words[wi] & ((bi == 63) ? ~0ull : ((2ull << bi) - 1));
                int cnt = 0;
                while (cnt < 4) {
                    if (m == 0) { if (wi == 0) break; m = words[--wi]; continue; }
                    int p = 63 - __clzll(m);
                    f[cnt++] = (ushort)(wi * 64 + p);
                    m &= ~(1ull << p);
                }
            }
            {   // backward: first 4 set bits >= l, value min(p+1, L-1)
                int wi = l >> 6, bi = l & 63;
                uint64_t m = words[wi] & (~0ull << bi);
                int cnt = 0;
                while (cnt < 4) {
                    if (m == 0) { if (wi == (LSEQ / 64) - 1) break; m = words[++wi]; continue; }
                    int p = __ffsll((long long)m) - 1;
                    int pos = wi * 64 + p;
                    g[cnt++] = (ushort)((pos >= LSEQ - 1) ? (LSEQ - 1) : (pos + 1));
                    m &= m - 1;
                }
            }
        }
        uint4 pk;
        pk.x = (uint32_t)f[0] | ((uint32_t)f[1] << 16);
        pk.y = (uint32_t)f[2] | ((uint32_t)f[3] << 16);
        pk.z = (uint32_t)g[0] | ((uint32_t)g[1] << 16);
        pk.w = (uint32_t)g[2] | ((uint32_t)g[3] << 16);
        *(uint4*)(idxb + (((size_t)(b * LSEQ + l)) * NH + h) * 8) = pk;
    }
}

// ---------------- weighted 8-way gather ----------------
__global__ __launch_bounds__(256) void gather_kernel(
    const float* __restrict__ V1,
    const short* __restrict__ idxb,
    const float* __restrict__ bw,
    float* __restrict__ out)
{
    int wid  = (blockIdx.x * 256 + threadIdx.x) >> 6;
    int lane = threadIdx.x & 63;
    int gr   = wid >> 4;
    int h    = wid & 15;
    int b    = gr >> 11;

    const ushort4* ip = (const ushort4*)(idxb + ((size_t)gr * NH + h) * 8);
    ushort4 i0 = ip[0];
    ushort4 i1 = ip[1];

    const float* wp    = bw + h * 8;
    const float* vbase = V1 + (size_t)b * LSEQ * NKV + h * HD + lane;

    float acc = wp[0] * vbase[(size_t)i0.x * NKV] + wp[1] * vbase[(size_t)i0.y * NKV] +
                wp[2] * vbase[(size_t)i0.z * NKV] + wp[3] * vbase[(size_t)i0.w * NKV] +
                wp[4] * vbase[(size_t)i1.x * NKV] + wp[5] * vbase[(size_t)i1.y * NKV] +
                wp[6] * vbase[(size_t)i1.z * NKV] + wp[7] * vbase[(size_t)i1.w * NKV];

    out[(size_t)gr * NKV + h * HD + lane] = acc;
}

extern "C" void kernel_launch(void* const* d_in, const int* in_sizes, int n_in,
                              void* d_out, int out_size, void* d_ws, size_t ws_size,
                              hipStream_t stream)
{
    const float* hs = (const float*)d_in[0];  // [4,2048,1024]
    const float* Wk = (const float*)d_in[1];  // [1024,1024]
    const float* bk = (const float*)d_in[2];  // [1024]
    const float* Wv = (const float*)d_in[3];  // [1024,1024]
    const float* bv = (const float*)d_in[4];  // [1024]
    const float* RH = (const float*)d_in[5];  // [16,64]
    const float* bw = (const float*)d_in[6];  // [16,8]
    float* out = (float*)d_out;

    char* ws = (char*)d_ws;
    size_t o = 0;
    float* V1      = (float*)(ws + o);  o += (size_t)M_TOT * NKV * 4;      // 32 MiB
    ushort* Ahi    = (ushort*)(ws + o); o += (size_t)M_TOT * HID * 2;      // 16 MiB
    ushort* Alo    = (ushort*)(ws + o); o += (size_t)M_TOT * HID * 2;      // 16 MiB
    ushort* WvhiT  = (ushort*)(ws + o); o += (size_t)HID * NKV * 2;        // 2 MiB
    ushort* WvloT  = (ushort*)(ws + o); o += (size_t)HID * NKV * 2;
    ushort* WkhiT  = (ushort*)(ws + o); o += (size_t)HID * NKV * 2;
    ushort* WkloT  = (ushort*)(ws + o); o += (size_t)HID * NKV * 2;
    unsigned char* validB = (unsigned char*)(ws + o); o += (size_t)BS * NH * LSEQ; // 128 KiB
    short* idxb    = (short*)(ws + o);  o += (size_t)M_TOT * NH * 8 * 2;   // 2 MiB

    prep<<<8192 + 512, 256, 0, stream>>>(hs, Wv, Wk, Ahi, Alo,
                                         WvhiT, WvloT, WkhiT, WkloT);
    mfma_gemm<<<dim3(M_TOT / 256, 8), 512, 0, stream>>>(
        Ahi, Alo, WvhiT, WvloT, WkhiT, WkloT, bv, bk, RH, V1, validB);
    scan_kernel<<<BS * NH, 256, 0, stream>>>(validB, idxb);
    gather_kernel<<<(M_TOT * NH) / 4, 256, 0, stream>>>(V1, idxb, bw, out);
}

// Round 10
// 224.778 us; speedup vs baseline: 1.0227x; 1.0227x over previous
//
#include <hip/hip_runtime.h>
#include <hip/hip_bf16.h>
#include <stdint.h>

// Problem constants
#define BS   4
#define LSEQ 2048
#define HID  1024
#define NH   16
#define HD   64
#define M_TOT (BS * LSEQ)   // 8192
#define NKV   (NH * HD)     // 1024

typedef __attribute__((ext_vector_type(8))) short short8x;   // 8 bf16
typedef __attribute__((ext_vector_type(4))) float f32x4;     // MFMA accum

__device__ __forceinline__ float relu_f(float x) { return x > 0.0f ? x : 0.0f; }

__device__ __forceinline__ ushort bf16_rne(float f) {
    uint32_t x = __float_as_uint(f);
    return (ushort)((x + 0x7FFFu + ((x >> 16) & 1u)) >> 16);
}
__device__ __forceinline__ float bf16_to_f(ushort h) {
    return __uint_as_float((uint32_t)h << 16);
}

__device__ __forceinline__ void gload_lds16(const void* g, void* l) {
    typedef __attribute__((address_space(1))) const uint32_t GU;
    typedef __attribute__((address_space(3))) uint32_t LU;
    __builtin_amdgcn_global_load_lds((GU*)g, (LU*)l, 16, 0, 0);
}

// ---------------- fused prep: A hi/lo split + both W hi/lo transposed splits ----------------
__global__ __launch_bounds__(256) void prep(
    const float* __restrict__ A,
    const float* __restrict__ Wv, const float* __restrict__ Wk,
    ushort* __restrict__ Ahi, ushort* __restrict__ Alo,
    ushort* __restrict__ WvhiT, ushort* __restrict__ WvloT,
    ushort* __restrict__ WkhiT, ushort* __restrict__ WkloT)
{
    __shared__ float t[64][65];
    const int bid = blockIdx.x;
    const int tid = threadIdx.x;
    if (bid < 8192) {
        int i = bid * 256 + tid;
        float4 v = ((const float4*)A)[i];
        ushort4 h, l;
        h.x = bf16_rne(v.x); l.x = bf16_rne(v.x - bf16_to_f(h.x));
        h.y = bf16_rne(v.y); l.y = bf16_rne(v.y - bf16_to_f(h.y));
        h.z = bf16_rne(v.z); l.z = bf16_rne(v.z - bf16_to_f(h.z));
        h.w = bf16_rne(v.w); l.w = bf16_rne(v.w - bf16_to_f(h.w));
        ((ushort4*)Ahi)[i] = h;
        ((ushort4*)Alo)[i] = l;
    } else {
        int idx = bid - 8192;                 // 0..511
        const float* W  = (idx < 256) ? Wv : Wk;
        ushort* hiT     = (idx < 256) ? WvhiT : WkhiT;
        ushort* loT     = (idx < 256) ? WvloT : WkloT;
        int tt = idx & 255;
        int k0 = (tt >> 4) * 64, n0 = (tt & 15) * 64;
#pragma unroll
        for (int it = 0; it < 4; ++it) {
            int r = it * 16 + (tid >> 4);
            int c = (tid & 15) * 4;
            float4 v = *(const float4*)&W[(size_t)(k0 + r) * NKV + n0 + c];
            t[r][c] = v.x; t[r][c + 1] = v.y; t[r][c + 2] = v.z; t[r][c + 3] = v.w;
        }
        __syncthreads();
        int n  = tid >> 2;            // 0..63
        int kc = (tid & 3) * 16;      // 0,16,32,48
        ushort hb[16], lb[16];
#pragma unroll
        for (int j = 0; j < 16; ++j) {
            float f = t[kc + j][n];
            ushort h = bf16_rne(f);
            hb[j] = h;
            lb[j] = bf16_rne(f - bf16_to_f(h));
        }
        size_t o = (size_t)(n0 + n) * 1024 + k0 + kc;
        *(uint4*)&hiT[o]     = *(uint4*)&hb[0];
        *(uint4*)&hiT[o + 8] = *(uint4*)&hb[8];
        *(uint4*)&loT[o]     = *(uint4*)&lb[0];
        *(uint4*)&loT[o + 8] = *(uint4*)&lb[8];
    }
}

// ---------------- 128x128 split-bf16 MFMA GEMM (round-4 proven template) ----------------
// grid (64, 16): y 0..7 -> V path (Wv, 2-term, 32 K-tiles, bf16 V1 out),
//                y 8..15 -> K path (Wk, 3-term, 48 K-tiles, dot+threshold).
// V: C = Ahi@Whi + Alo@Whi            (err ~2e-3 vs 3-term, << 0.071 threshold)
// K: C = Ahi@Whi + Alo@Whi + Ahi@Wlo  (bit-identical to round-4, dot accuracy)
__global__ __launch_bounds__(256, 2) void mfma_gemm(
    const ushort* __restrict__ Ahi, const ushort* __restrict__ Alo,
    const ushort* __restrict__ WvhiT, const ushort* __restrict__ WvloT,
    const ushort* __restrict__ WkhiT, const ushort* __restrict__ WkloT,
    const float* __restrict__ bv, const float* __restrict__ bk,
    const float* __restrict__ RH,
    ushort* __restrict__ V1b, unsigned char* __restrict__ validB)
{
    __shared__ ushort As[128 * 64];   // 16 KB, XOR-swizzled 16B chunks
    __shared__ ushort Bsh[128 * 64];  // 16 KB

    const int tid  = threadIdx.x;
    const int lane = tid & 63;
    const int wv   = tid >> 6;        // wave 0..3
    const int wm   = wv >> 1;         // wave row 0/1
    const int wn   = wv & 1;          // wave col 0/1
    const int bm   = blockIdx.x;
    const bool kpath = (blockIdx.y >= 8);
    const int bn   = blockIdx.y & 7;

    const ushort* WT_hi = kpath ? WkhiT : WvhiT;
    const ushort* WT_lo = kpath ? WkloT : WvloT;
    const float*  bias  = kpath ? bk : bv;
    const int KS = kpath ? 48 : 32;   // V path drops the Ahi@Wlo term

    f32x4 acc[4][4];
    const f32x4 z = {0.f, 0.f, 0.f, 0.f};
#pragma unroll
    for (int i = 0; i < 4; ++i)
#pragma unroll
        for (int j = 0; j < 4; ++j) acc[i][j] = z;

    for (int ks = 0; ks < KS; ++ks) {
        const int seg = ks >> 4;
        const int k0  = (ks & 15) << 6;
        const ushort* Aseg = (seg == 1) ? Alo : Ahi;
        const ushort* Wseg = (seg == 2) ? WT_lo : WT_hi;

#pragma unroll
        for (int it = 0; it < 4; ++it) {
            int f = it * 256 + tid;
            int r = f >> 3, c = f & 7;
            const ushort* asrc = Aseg + (size_t)(bm * 128 + r) * 1024 + k0 + ((c ^ (r & 7)) << 3);
            gload_lds16(asrc, &As[(size_t)(it * 256 + wv * 64) * 8]);
        }
#pragma unroll
        for (int it = 0; it < 4; ++it) {
            int f = it * 256 + tid;
            int r = f >> 3, c = f & 7;
            const ushort* bsrc = Wseg + (size_t)(bn * 128 + r) * 1024 + k0 + ((c ^ (r & 7)) << 3);
            gload_lds16(bsrc, &Bsh[(size_t)(it * 256 + wv * 64) * 8]);
        }
        __syncthreads();

        short8x a[4][2], b[4][2];
#pragma unroll
        for (int mi = 0; mi < 4; ++mi)
#pragma unroll
            for (int k2 = 0; k2 < 2; ++k2) {
                int row = wm * 64 + mi * 16 + (lane & 15);
                int ch  = k2 * 4 + (lane >> 4);
                a[mi][k2] = *(const short8x*)((const char*)As + row * 128 + ((ch ^ (row & 7)) << 4));
            }
#pragma unroll
        for (int ni = 0; ni < 4; ++ni)
#pragma unroll
            for (int k2 = 0; k2 < 2; ++k2) {
                int row = wn * 64 + ni * 16 + (lane & 15);
                int ch  = k2 * 4 + (lane >> 4);
                b[ni][k2] = *(const short8x*)((const char*)Bsh + row * 128 + ((ch ^ (row & 7)) << 4));
            }

#pragma unroll
        for (int k2 = 0; k2 < 2; ++k2)
#pragma unroll
            for (int mi = 0; mi < 4; ++mi)
#pragma unroll
                for (int ni = 0; ni < 4; ++ni)
                    acc[mi][ni] = __builtin_amdgcn_mfma_f32_16x16x32_bf16(
                        a[mi][k2], b[ni][k2], acc[mi][ni], 0, 0, 0);
        __syncthreads();
    }

    // epilogue ; C/D layout: col = lane&15, row = (lane>>4)*4 + reg
    if (!kpath) {
#pragma unroll
        for (int mi = 0; mi < 4; ++mi)
#pragma unroll
            for (int ni = 0; ni < 4; ++ni) {
                int row0 = bm * 128 + wm * 64 + mi * 16 + (lane >> 4) * 4;
                int col  = bn * 128 + wn * 64 + ni * 16 + (lane & 15);
                float bc = bias[col];
#pragma unroll
                for (int r = 0; r < 4; ++r)
                    V1b[(size_t)(row0 + r) * NKV + col] =
                        bf16_rne(relu_f(acc[mi][ni][r] + bc));
            }
    } else {
        const int head = bn * 2 + wn;
        float rhw[4], bcs[4];
#pragma unroll
        for (int ni = 0; ni < 4; ++ni) {
            int ch = ni * 16 + (lane & 15);                 // col within head
            rhw[ni] = RH[head * HD + ch];
            bcs[ni] = bias[bn * 128 + wn * 64 + ch];
        }
#pragma unroll
        for (int mi = 0; mi < 4; ++mi) {
            float s[4];
#pragma unroll
            for (int r = 0; r < 4; ++r) {
                float v = 0.f;
#pragma unroll
                for (int ni = 0; ni < 4; ++ni)
                    v += relu_f(acc[mi][ni][r] + bcs[ni]) * rhw[ni];
                s[r] = v;
            }
#pragma unroll
            for (int m = 1; m < 16; m <<= 1)
#pragma unroll
                for (int r = 0; r < 4; ++r)
                    s[r] += __shfl_xor(s[r], m);
            if ((lane & 15) == 0) {
#pragma unroll
                for (int r = 0; r < 4; ++r) {
                    int grow = bm * 128 + wm * 64 + mi * 16 + (lane >> 4) * 4 + r;
                    int bb = grow >> 11, ll = grow & 2047;
                    validB[((size_t)bb * NH + head) * LSEQ + ll] = (s[r] > 0.5f) ? 1 : 0;
                }
            }
        }
    }
}

// ---------------- parallel register-map extraction ----------------
__global__ __launch_bounds__(256) void scan_kernel(
    const unsigned char* __restrict__ validB,
    short* __restrict__ idxb)   // [M_TOT][NH][8]: slots 0..3 fwd, 4..7 bwd
{
    const int bh = blockIdx.x;      // 0..63
    const int b  = bh >> 4;
    const int h  = bh & 15;
    const unsigned char* v = validB + ((size_t)b * NH + h) * LSEQ;

    __shared__ uint64_t words[LSEQ / 64];

    const int tid  = threadIdx.x;
    const int lane = tid & 63;
    const int wv   = tid >> 6;

#pragma unroll
    for (int it = 0; it < LSEQ / 256; ++it) {
        int p = it * 256 + wv * 64 + lane;
        uint64_t m = __ballot(v[p] != 0);
        if (lane == 0) {
            if ((p >> 6) == 0) m &= ~1ull;
            words[p >> 6] = m;
        }
    }
    __syncthreads();

#pragma unroll
    for (int it = 0; it < LSEQ / 256; ++it) {
        int l = it * 256 + tid;
        ushort f[4] = {0, 0, 0, 0};
        ushort g[4] = {0, 0, 0, 0};
        if (l > 0) {
            {   // forward: last 4 set bits <= l
                int wi = l >> 6, bi = l & 63;
                uint64_t m = words[wi] & ((bi == 63) ? ~0ull : ((2ull << bi) - 1));
                int cnt = 0;
                while (cnt < 4) {
                    if (m == 0) { if (wi == 0) break; m = words[--wi]; continue; }
                    int p = 63 - __clzll(m);
                    f[cnt++] = (ushort)(wi * 64 + p);
                    m &= ~(1ull << p);
                }
            }
            {   // backward: first 4 set bits >= l, value min(p+1, L-1)
                int wi = l >> 6, bi = l & 63;
                uint64_t m = words[wi] & (~0ull << bi);
                int cnt = 0;
                while (cnt < 4) {
                    if (m == 0) { if (wi == (LSEQ / 64) - 1) break; m = words[++wi]; continue; }
                    int p = __ffsll((long long)m) - 1;
                    int pos = wi * 64 + p;
                    g[cnt++] = (ushort)((pos >= LSEQ - 1) ? (LSEQ - 1) : (pos + 1));
                    m &= m - 1;
                }
            }
        }
        uint4 pk;
        pk.x = (uint32_t)f[0] | ((uint32_t)f[1] << 16);
        pk.y = (uint32_t)f[2] | ((uint32_t)f[3] << 16);
        pk.z = (uint32_t)g[0] | ((uint32_t)g[1] << 16);
        pk.w = (uint32_t)g[2] | ((uint32_t)g[3] << 16);
        *(uint4*)(idxb + (((size_t)(b * LSEQ + l)) * NH + h) * 8) = pk;
    }
}

// ---------------- weighted 8-way gather (bf16 V1) ----------------
__global__ __launch_bounds__(256) void gather_kernel(
    const ushort* __restrict__ V1b,
    const short* __restrict__ idxb,
    const float* __restrict__ bw,
    float* __restrict__ out)
{
    int wid  = (blockIdx.x * 256 + threadIdx.x) >> 6;
    int lane = threadIdx.x & 63;
    int gr   = wid >> 4;
    int h    = wid & 15;
    int b    = gr >> 11;

    const ushort4* ip = (const ushort4*)(idxb + ((size_t)gr * NH + h) * 8);
    ushort4 i0 = ip[0];
    ushort4 i1 = ip[1];

    const float* wp     = bw + h * 8;
    const ushort* vbase = V1b + (size_t)b * LSEQ * NKV + h * HD + lane;

    float acc = wp[0] * bf16_to_f(vbase[(size_t)i0.x * NKV]) +
                wp[1] * bf16_to_f(vbase[(size_t)i0.y * NKV]) +
                wp[2] * bf16_to_f(vbase[(size_t)i0.z * NKV]) +
                wp[3] * bf16_to_f(vbase[(size_t)i0.w * NKV]) +
                wp[4] * bf16_to_f(vbase[(size_t)i1.x * NKV]) +
                wp[5] * bf16_to_f(vbase[(size_t)i1.y * NKV]) +
                wp[6] * bf16_to_f(vbase[(size_t)i1.z * NKV]) +
                wp[7] * bf16_to_f(vbase[(size_t)i1.w * NKV]);

    out[(size_t)gr * NKV + h * HD + lane] = acc;
}

extern "C" void kernel_launch(void* const* d_in, const int* in_sizes, int n_in,
                              void* d_out, int out_size, void* d_ws, size_t ws_size,
                              hipStream_t stream)
{
    const float* hs = (const float*)d_in[0];  // [4,2048,1024]
    const float* Wk = (const float*)d_in[1];  // [1024,1024]
    const float* bk = (const float*)d_in[2];  // [1024]
    const float* Wv = (const float*)d_in[3];  // [1024,1024]
    const float* bv = (const float*)d_in[4];  // [1024]
    const float* RH = (const float*)d_in[5];  // [16,64]
    const float* bw = (const float*)d_in[6];  // [16,8]
    float* out = (float*)d_out;

    char* ws = (char*)d_ws;
    size_t o = 0;
    ushort* V1b    = (ushort*)(ws + o); o += (size_t)M_TOT * NKV * 2;      // 16 MiB
    ushort* Ahi    = (ushort*)(ws + o); o += (size_t)M_TOT * HID * 2;      // 16 MiB
    ushort* Alo    = (ushort*)(ws + o); o += (size_t)M_TOT * HID * 2;      // 16 MiB
    ushort* WvhiT  = (ushort*)(ws + o); o += (size_t)HID * NKV * 2;        // 2 MiB
    ushort* WvloT  = (ushort*)(ws + o); o += (size_t)HID * NKV * 2;
    ushort* WkhiT  = (ushort*)(ws + o); o += (size_t)HID * NKV * 2;
    ushort* WkloT  = (ushort*)(ws + o); o += (size_t)HID * NKV * 2;
    unsigned char* validB = (unsigned char*)(ws + o); o += (size_t)BS * NH * LSEQ; // 128 KiB
    short* idxb    = (short*)(ws + o);  o += (size_t)M_TOT * NH * 8 * 2;   // 2 MiB

    prep<<<8192 + 512, 256, 0, stream>>>(hs, Wv, Wk, Ahi, Alo,
                                         WvhiT, WvloT, WkhiT, WkloT);
    mfma_gemm<<<dim3(M_TOT / 128, 16), 256, 0, stream>>>(
        Ahi, Alo, WvhiT, WvloT, WkhiT, WkloT, bv, bk, RH, V1b, validB);
    scan_kernel<<<BS * NH, 256, 0, stream>>>(validB, idxb);
    gather_kernel<<<(M_TOT * NH) / 4, 256, 0, stream>>>(V1b, idxb, bw, out);
}